// Round 7
// baseline (257.901 us; speedup 1.0000x reference)
//
#include <hip/hip_runtime.h>
#include <hip/hip_fp16.h>
#include <math.h>

typedef _Float16 f16;
typedef _Float16 f16x8 __attribute__((ext_vector_type(8)));
typedef _Float16 f16x4 __attribute__((ext_vector_type(4)));
typedef float f32x4 __attribute__((ext_vector_type(4)));

namespace {
constexpr int kB = 32, kD = 512, kN = 1024, kF = 256;
constexpr float kScale = 0.04419417382415922f;   // 1/sqrt(512)
constexpr float kLogMarg = -6.931471805599453f;  // -log(1024)
constexpr float kPInv = 1.f / 16384.f;           // undo evp's 2^14 lift
}

// global -> LDS direct DMA, 16B per lane. LDS dest is wave-uniform base +
// lane*16 (hardware); global src is per-lane.
__device__ __forceinline__ void gload16(const void* g, void* l) {
  __builtin_amdgcn_global_load_lds(
      (const __attribute__((address_space(1))) void*)g,
      (__attribute__((address_space(3))) void*)l, 16, 0, 0);
}

// ---- K1: val = x[b,c,i] + pos(c,i); emit xfT[lb,c,i] and xf[lb,i,c] (f16) --
__global__ __launch_bounds__(256) void k_prep(
    const float* __restrict__ x, const float* __restrict__ re,
    const float* __restrict__ ce, f16* __restrict__ xf,
    f16* __restrict__ xfT, int b0) {
  __shared__ f16 T[64][68];
  const int lb = blockIdx.z;
  const int i0 = blockIdx.x * 64, c0 = blockIdx.y * 64;
  const int t = threadIdx.x;
  const int il = (t & 15) * 4;  // 0..60
  const int cl = t >> 4;        // 0..15
  const size_t xbase = ((size_t)(b0 + lb) * kD) * kN;
#pragma unroll
  for (int p = 0; p < 4; p++) {
    const int c = c0 + cl + 16 * p;
    const int i = i0 + il;
    const float4 xv = *(const float4*)(x + xbase + (size_t)c * kN + i);
    float4 pv;
    if (c < kF) {  // wave-uniform per block (c0 multiple of 64)
      pv.x = ce[((i + 0) & 31) * kF + c];
      pv.y = ce[((i + 1) & 31) * kF + c];
      pv.z = ce[((i + 2) & 31) * kF + c];
      pv.w = ce[((i + 3) & 31) * kF + c];
    } else {
      const float r = re[(i >> 5) * kF + (c - kF)];
      pv.x = r; pv.y = r; pv.z = r; pv.w = r;
    }
    const f16 h0 = (f16)(xv.x + pv.x), h1 = (f16)(xv.y + pv.y);
    const f16 h2 = (f16)(xv.z + pv.z), h3 = (f16)(xv.w + pv.w);
    f16* dT = xfT + ((size_t)lb * kD + c) * kN + i;
    *(f16x4*)dT = (f16x4){h0, h1, h2, h3};
    T[cl + 16 * p][il + 0] = h0; T[cl + 16 * p][il + 1] = h1;
    T[cl + 16 * p][il + 2] = h2; T[cl + 16 * p][il + 3] = h3;
  }
  __syncthreads();
#pragma unroll
  for (int p = 0; p < 4; p++) {
    const int ir = cl + 16 * p;  // local i
    const int cc = il;           // local c
    const f16 h0 = T[cc + 0][ir], h1 = T[cc + 1][ir];
    const f16 h2 = T[cc + 2][ir], h3 = T[cc + 3][ir];
    f16* dF = xf + ((size_t)lb * kN + i0 + ir) * kD + c0 + cc;
    *(f16x4*)dF = (f16x4){h0, h1, h2, h3};
  }
}

// ---- K2: S16 = f16(kScale * xf @ xf^T) -------------------------------------
// R2-measured config (best for K=512): 128x128 tile, 4 waves, BK=64, 2-deep
// double-buffer (64 KB LDS -> 2 blocks/CU TLP), issue-next-then-compute,
// one __syncthreads per K-step. T1 XCD swizzle + T2 XOR swizzle + gload_lds.
__global__ __launch_bounds__(256) void k_gemm_s(
    const f16* __restrict__ xf, f16* __restrict__ S16,
    float* __restrict__ rp) {
  __shared__ char sm[65536];  // buf0: A[0:16K) B[16K:32K); buf1: +32K
  const int nwg = (int)(gridDim.x * gridDim.y * gridDim.z);  // 64*g, %8==0
  const int lin = (int)(blockIdx.x +
                        gridDim.x * (blockIdx.y + gridDim.y * blockIdx.z));
  const int wid = (lin & 7) * (nwg >> 3) + (lin >> 3);
  const int bx = wid & 7, by = (wid >> 3) & 7, bz = wid >> 6;

  const int lb = bz;
  const int i0 = by * 128, j0 = bx * 128;
  const char* base = (const char*)(xf + (size_t)lb * kN * kD);
  const int t = threadIdx.x;
  const int w = t >> 6, lane = t & 63;
  const int m_off = (w >> 1) * 64, n_off = (w & 1) * 64;
  const int quad = lane >> 4, l15 = lane & 15;
  const int swz = (l15 & 7) << 4;

  // staging: 4 chunks x (4 waves x 1KB). linear LDS off = p*4096+w*1024+lane*16
  int srcA[4], srcB[4], ldsw[4];
#pragma unroll
  for (int p = 0; p < 4; p++) {
    const int off = p * 4096 + w * 1024 + lane * 16;
    const int r = off >> 7;                       // tile row 0..127
    const int cb = (off & 127) ^ ((r & 7) << 4);  // inverse-swizzled src col
    srcA[p] = (i0 + r) * (kD * 2) + cb;           // row stride 1024 B
    srcB[p] = (j0 + r) * (kD * 2) + cb;
    ldsw[p] = p * 4096 + w * 1024;                // wave-uniform LDS base
  }

  f32x4 acc[4][4];
#pragma unroll
  for (int a = 0; a < 4; a++)
#pragma unroll
    for (int b = 0; b < 4; b++) acc[a][b] = (f32x4){0.f, 0.f, 0.f, 0.f};

  // prologue: stage K-tile 0 into buf0
#pragma unroll
  for (int p = 0; p < 4; p++) gload16(base + srcA[p], sm + ldsw[p]);
#pragma unroll
  for (int p = 0; p < 4; p++) gload16(base + srcB[p], sm + 16384 + ldsw[p]);
  __syncthreads();

#pragma unroll
  for (int tt = 0; tt < 8; tt++) {  // 8 K-tiles of 64 f16 (128 B)
    const int cur = tt & 1, nxt = cur ^ 1;
    if (tt + 1 < 8) {  // issue next tile's loads FIRST (overlap with compute)
      const int k0b = (tt + 1) * 128;
#pragma unroll
      for (int p = 0; p < 4; p++)
        gload16(base + srcA[p] + k0b, sm + (nxt << 15) + ldsw[p]);
#pragma unroll
      for (int p = 0; p < 4; p++)
        gload16(base + srcB[p] + k0b, sm + (nxt << 15) + 16384 + ldsw[p]);
    }
    const char* bA = sm + (cur << 15);
    const char* bB = bA + 16384;
#pragma unroll
    for (int kk = 0; kk < 2; kk++) {
      f16x8 af[4], bf[4];
#pragma unroll
      for (int q = 0; q < 4; q++)
        af[q] = *(const f16x8*)(bA + (m_off + 16 * q + l15) * 128 +
                                ((kk * 64 + quad * 16) ^ swz));
#pragma unroll
      for (int q = 0; q < 4; q++)
        bf[q] = *(const f16x8*)(bB + (n_off + 16 * q + l15) * 128 +
                                ((kk * 64 + quad * 16) ^ swz));
#pragma unroll
      for (int qa = 0; qa < 4; qa++)
#pragma unroll
        for (int qb = 0; qb < 4; qb++)
          acc[qa][qb] = __builtin_amdgcn_mfma_f32_16x16x32_f16(
              af[qa], bf[qb], acc[qa][qb], 0, 0, 0);
    }
    __syncthreads();  // drains vmcnt (next tile ready) + protects cur reuse
  }

  f16* Sb = S16 + (size_t)lb * kN * kN;
  const int jt2 = bx * 2 + (w & 1);
  float* rpb = rp + ((size_t)lb * 16 + jt2) * kN + i0 + m_off;
#pragma unroll
  for (int qa = 0; qa < 4; qa++) {
    const int i = i0 + m_off + 16 * qa + quad * 4;
    float rs[4] = {0.f, 0.f, 0.f, 0.f};
#pragma unroll
    for (int qb = 0; qb < 4; qb++) {
      const int j = j0 + n_off + 16 * qb + l15;
#pragma unroll
      for (int r = 0; r < 4; r++) {
        const f16 h = (f16)(acc[qa][qb][r] * kScale);
        Sb[(size_t)(i + r) * kN + j] = h;
        rs[r] += __expf((float)h);
      }
    }
#pragma unroll
    for (int r = 0; r < 4; r++) {
      float s = rs[r];
      s += __shfl_xor(s, 1);
      s += __shfl_xor(s, 2);
      s += __shfl_xor(s, 4);
      s += __shfl_xor(s, 8);
      if (l15 == 0) rpb[16 * qa + 4 * quad + r] = s;
    }
  }
}

// ---- K3: u[lb,i] = -log(n) - log(sum of 16 row partials) -------------------
__global__ __launch_bounds__(256) void k_u(
    const float* __restrict__ rp, float* __restrict__ u) {
  const int lb = blockIdx.y;
  const int i = blockIdx.x * 256 + threadIdx.x;
  const float* r = rp + (size_t)lb * 16 * kN + i;
  float s = 0.f;
#pragma unroll
  for (int t = 0; t < 16; t++) s += r[(size_t)t * kN];
  u[lb * kN + i] = kLogMarg - __logf(s);
}

// ---- K4: column partial sums of exp(S16 + u_i), row-major vectorized -------
// Each thread owns 4 consecutive columns, loops 64 rows: f16x4 coalesced
// reads (512 B per wave-instr vs old 128 B), uniform u[r] scalar loads.
__global__ __launch_bounds__(256) void k_cs(
    const f16* __restrict__ S16, const float* __restrict__ u,
    float* __restrict__ cp) {
  const int lb = blockIdx.z;
  const int seg = blockIdx.y;
  const int j = threadIdx.x * 4;
  const f16* Sb = S16 + (size_t)lb * kN * kN + (size_t)(seg * 64) * kN + j;
  const float* ub = u + lb * kN + seg * 64;
  float s0 = 0.f, s1 = 0.f, s2 = 0.f, s3 = 0.f;
#pragma unroll 8
  for (int r = 0; r < 64; r++) {
    const f16x4 v = *(const f16x4*)(Sb + (size_t)r * kN);
    const float ur = ub[r];
    s0 += __expf((float)v[0] + ur);
    s1 += __expf((float)v[1] + ur);
    s2 += __expf((float)v[2] + ur);
    s3 += __expf((float)v[3] + ur);
  }
  float4 o = {s0, s1, s2, s3};
  *(float4*)(cp + ((size_t)lb * 16 + seg) * kN + j) = o;
}

// ---- K5: evp[lb,j] = 2^14 * exp(v_j) = 16 / colsum_j -----------------------
__global__ __launch_bounds__(256) void k_v(
    const float* __restrict__ cp, float* __restrict__ evp) {
  const int lb = blockIdx.y;
  const int j = blockIdx.x * 256 + threadIdx.x;
  const float* c = cp + (size_t)lb * 16 * kN + j;
  float s = 0.f;
#pragma unroll
  for (int r = 0; r < 16; r++) s += c[(size_t)r * kN];
  evp[lb * kN + j] = 16.f / s;
}

// Per-phase fragment read + MFMA cluster (gemm_o).
#define AF_READ(q)                                                          \
  _Pragma("unroll")                                                         \
  for (int pa = 0; pa < 2; pa++)                                            \
    _Pragma("unroll")                                                       \
    for (int kk = 0; kk < 2; kk++)                                          \
      af[pa][kk] = *(const f16x8*)(bA + (m_off + 32*(q) + 16*pa + l15)*128  \
                                   + ((kk*64 + quad*16) ^ swz));

#define MFMA_PH(q)                                                          \
  __builtin_amdgcn_s_setprio(1);                                            \
  _Pragma("unroll")                                                         \
  for (int pa = 0; pa < 2; pa++)                                            \
    _Pragma("unroll")                                                       \
    for (int qb = 0; qb < 4; qb++)                                          \
      _Pragma("unroll")                                                     \
      for (int kk = 0; kk < 2; kk++)                                        \
        acc[2*(q)+pa][qb] = __builtin_amdgcn_mfma_f32_16x16x32_f16(         \
            af[pa][kk], bf[qb][kk], acc[2*(q)+pa][qb], 0, 0, 0);            \
  __builtin_amdgcn_s_setprio(0);

// ---- K6: out[b,c,i] = (1/2^14) * sum_j xfT[c,j] * t16[i,j], with -----------
// t16[i,j] = f16(exp(S16[i,j]+u_i) * evp_j) computed IN-REGISTER at P0 from
// raw-staged S16 (k_pt eliminated). Staging/schedule = R5 deep-lead counted
// vmcnt, UNCHANGED (B=raw S16 via gload_lds; exp transform is ds_read->VALU->
// MFMA, hides under matrix pipe). u per B-row in 4 VGPRs (rows wave-fixed);
// evp (=16/colsum, includes 2^14) staged once into 4 KB LDS.
__global__ __launch_bounds__(512) void k_gemm_o(
    const f16* __restrict__ xfT, const f16* __restrict__ S16,
    const float* __restrict__ u, const float* __restrict__ evp,
    float* __restrict__ out, int b0) {
  __shared__ char sm[135168];  // A dbuf 0/32K, B dbuf 64K/96K, evp @128K
  const int nwg = (int)(gridDim.x * gridDim.y * gridDim.z);  // 8*g, %8==0
  const int lin = (int)(blockIdx.x +
                        gridDim.x * (blockIdx.y + gridDim.y * blockIdx.z));
  const int wid = (lin & 7) * (nwg >> 3) + (lin >> 3);
  const int bx = wid & 3, by = (wid >> 2) & 1, bz = wid >> 3;

  const int lb = bz;
  const int i0 = bx * 256, c0 = by * 256;
  const char* Ab = (const char*)(xfT + (size_t)lb * kD * kN);  // rows c
  const char* Bb = (const char*)(S16 + (size_t)lb * kN * kN);  // rows i
  const int t = threadIdx.x;
  const int w = t >> 6, lane = t & 63;
  const int wm = w >> 2, wn = w & 3;
  const int m_off = wm * 128, n_off = wn * 64;
  const int quad = lane >> 4, l15 = lane & 15;
  const int swz = (l15 & 7) << 4;

  int srcA[4], srcB[4], ldsw[4];
#pragma unroll
  for (int p = 0; p < 4; p++) {
    const int off = p * 8192 + t * 16;
    const int r = off >> 7;
    const int cb = (off & 127) ^ ((r & 7) << 4);
    srcA[p] = (c0 + r) * (kN * 2) + cb;  // row stride 2048 B
    srcB[p] = (i0 + r) * (kN * 2) + cb;
    ldsw[p] = p * 8192 + w * 1024;
  }

  // one-time: evp -> LDS (4 KB); u for this wave's 64 B-rows -> 4 VGPRs.
  float* evl = (float*)(sm + 131072);
  *(float2*)(evl + t * 2) = *(const float2*)(evp + (size_t)lb * kN + t * 2);
  float u4[4];
  const float* ub = u + (size_t)lb * kN + i0 + n_off + l15;
#pragma unroll
  for (int qb = 0; qb < 4; qb++) u4[qb] = ub[16 * qb];
  // Drain compiler-tracked loads + evl ds_write BEFORE issuing counted gloads
  // so manual vmcnt(N) accounting sees ONLY gload_lds in flight.
  asm volatile("s_waitcnt vmcnt(0) lgkmcnt(0)" ::: "memory");
  __builtin_amdgcn_sched_barrier(0);

  // prologue: B(0)x4, A{0,2}(0), A{1,3}(0), B(1)x4 -> vmcnt(6) proves
  // B(0)+A{0,2}(0); A{1,3}(0)+B(1) stay in flight.
#pragma unroll
  for (int p = 0; p < 4; p++) gload16(Bb + srcB[p], sm + 65536 + ldsw[p]);
  gload16(Ab + srcA[0], sm + ldsw[0]);
  gload16(Ab + srcA[2], sm + ldsw[2]);
  gload16(Ab + srcA[1], sm + ldsw[1]);
  gload16(Ab + srcA[3], sm + ldsw[3]);
#pragma unroll
  for (int p = 0; p < 4; p++)
    gload16(Bb + srcB[p] + 128, sm + 65536 + 32768 + ldsw[p]);
  f32x4 acc[8][4];
#pragma unroll
  for (int a = 0; a < 8; a++)
#pragma unroll
    for (int b = 0; b < 4; b++) acc[a][b] = (f32x4){0.f, 0.f, 0.f, 0.f};
  asm volatile("s_waitcnt vmcnt(6)" ::: "memory");
  __builtin_amdgcn_s_barrier();
  __builtin_amdgcn_sched_barrier(0);

#pragma unroll
  for (int tt = 0; tt < 16; tt++) {
    const int cur = tt & 1, nxt = cur ^ 1;
    const char* bA = sm + cur * 32768;
    const char* bB = sm + 65536 + cur * 32768;
    char* wA = sm + nxt * 32768;
    char* wB = sm + 65536 + cur * 32768;  // B(t+2) reuses slot of B(t)
    const int kA = (tt + 1) * 128, kBB = (tt + 2) * 128;
    f16x8 bf[4][2], af[2][2];
    // P0: raw S16 frags + af(0) + evp; drain; barrier; exp-transform; MFMA0
    f16x8 raw[4][2];
#pragma unroll
    for (int qb = 0; qb < 4; qb++)
#pragma unroll
      for (int kk = 0; kk < 2; kk++)
        raw[qb][kk] = *(const f16x8*)(bB + (n_off + 16 * qb + l15) * 128 +
                                      ((kk * 64 + quad * 16) ^ swz));
    AF_READ(0)
    float4 e0[2], e1[2];
#pragma unroll
    for (int kk = 0; kk < 2; kk++) {
      const float* ep = evl + tt * 64 + kk * 32 + quad * 8;
      e0[kk] = *(const float4*)ep;
      e1[kk] = *(const float4*)(ep + 4);
    }
    asm volatile("s_waitcnt lgkmcnt(0)" ::: "memory");
    __builtin_amdgcn_sched_barrier(0);
    __builtin_amdgcn_s_barrier();
#pragma unroll
    for (int qb = 0; qb < 4; qb++)
#pragma unroll
      for (int kk = 0; kk < 2; kk++) {
        f16x8 o;
        o[0] = (f16)(__expf((float)raw[qb][kk][0] + u4[qb]) * e0[kk].x);
        o[1] = (f16)(__expf((float)raw[qb][kk][1] + u4[qb]) * e0[kk].y);
        o[2] = (f16)(__expf((float)raw[qb][kk][2] + u4[qb]) * e0[kk].z);
        o[3] = (f16)(__expf((float)raw[qb][kk][3] + u4[qb]) * e0[kk].w);
        o[4] = (f16)(__expf((float)raw[qb][kk][4] + u4[qb]) * e1[kk].x);
        o[5] = (f16)(__expf((float)raw[qb][kk][5] + u4[qb]) * e1[kk].y);
        o[6] = (f16)(__expf((float)raw[qb][kk][6] + u4[qb]) * e1[kk].z);
        o[7] = (f16)(__expf((float)raw[qb][kk][7] + u4[qb]) * e1[kk].w);
        bf[qb][kk] = o;
      }
    MFMA_PH(0)
    // P1: issue A chunks 0,2 of t+1
    if (tt + 1 < 16) {
      gload16(Ab + srcA[0] + kA, wA + ldsw[0]);
      gload16(Ab + srcA[2] + kA, wA + ldsw[2]);
    }
    AF_READ(1)
    __builtin_amdgcn_s_barrier();
    MFMA_PH(1)
    if (tt == 15) { asm volatile("s_waitcnt vmcnt(0)" ::: "memory"); }
    else          { asm volatile("s_waitcnt vmcnt(6)" ::: "memory"); }
    __builtin_amdgcn_s_barrier();
    __builtin_amdgcn_sched_barrier(0);
    // P2
    AF_READ(2)
    __builtin_amdgcn_s_barrier();
    MFMA_PH(2)
    // P3: issue A chunks 1,3 of t+1 and all B of t+2
    if (tt + 1 < 16) {
      gload16(Ab + srcA[1] + kA, wA + ldsw[1]);
      gload16(Ab + srcA[3] + kA, wA + ldsw[3]);
    }
    if (tt + 2 < 16) {
#pragma unroll
      for (int p = 0; p < 4; p++)
        gload16(Bb + srcB[p] + kBB, wB + ldsw[p]);
    }
    AF_READ(3)
    __builtin_amdgcn_s_barrier();
    MFMA_PH(3)
    if (tt + 2 < 16)      { asm volatile("s_waitcnt vmcnt(6)" ::: "memory"); }
    else if (tt + 1 < 16) { asm volatile("s_waitcnt vmcnt(2)" ::: "memory"); }
    __builtin_amdgcn_s_barrier();
    __builtin_amdgcn_sched_barrier(0);
  }

  float* ob = out + ((size_t)(b0 + lb) * kD) * kN;
#pragma unroll
  for (int qa = 0; qa < 8; qa++) {
    const int c = c0 + m_off + 16 * qa + quad * 4;
#pragma unroll
    for (int qb = 0; qb < 4; qb++) {
      const int i = i0 + n_off + 16 * qb + l15;
#pragma unroll
      for (int r = 0; r < 4; r++)
        ob[(size_t)(c + r) * kN + i] = acc[qa][qb][r] * kPInv;
    }
  }
}

extern "C" void kernel_launch(void* const* d_in, const int* in_sizes, int n_in,
                              void* d_out, int out_size, void* d_ws, size_t ws_size,
                              hipStream_t stream) {
  const float* x = (const float*)d_in[0];
  const float* re = (const float*)d_in[1];
  const float* ce = (const float*)d_in[2];
  float* out = (float*)d_out;

  // ws per batch: S16 2MB + xf 1MB + xfT 1MB + u 4KB + evp 4KB
  //             + rp 64KB + cp 64KB = ~4.13 MB. 32x = 132 MB, ONE chunk.
  char* wsb = (char*)d_ws;
  const size_t perb = 2097152ull + 1048576 + 1048576 + 4096 + 4096 +
                      65536 + 65536;
  int G = (int)(ws_size / perb);
  if (G >= 32) G = 32;
  else if (G >= 16) G = 16;
  else if (G >= 8) G = 8;
  else if (G >= 4) G = 4;
  else if (G < 1) G = 1;
  f16* S16 = (f16*)wsb;
  f16* xf = (f16*)(wsb + (size_t)G * 2097152);
  f16* xfT = (f16*)((char*)xf + (size_t)G * 1048576);
  float* u = (float*)((char*)xfT + (size_t)G * 1048576);
  float* evp = u + (size_t)G * kN;
  float* rp = evp + (size_t)G * kN;           // [G][16][kN]
  float* cp = rp + (size_t)G * 16 * kN;       // [G][16][kN]

  for (int b0 = 0; b0 < kB; b0 += G) {
    const int g = (kB - b0 < G) ? (kB - b0) : G;
    k_prep<<<dim3(16, 8, g), 256, 0, stream>>>(x, re, ce, xf, xfT, b0);
    k_gemm_s<<<dim3(8, 8, g), 256, 0, stream>>>(xf, S16, rp);
    k_u<<<dim3(4, g), 256, 0, stream>>>(rp, u);
    k_cs<<<dim3(1, 16, g), 256, 0, stream>>>(S16, u, cp);
    k_v<<<dim3(4, g), 256, 0, stream>>>(cp, evp);
    k_gemm_o<<<dim3(4, 2, g), 512, 0, stream>>>(xfT, S16, u, evp, out, b0);
  }
}

// Round 8
// 237.956 us; speedup vs baseline: 1.0838x; 1.0838x over previous
//
#include <hip/hip_runtime.h>
#include <hip/hip_fp16.h>
#include <math.h>

typedef _Float16 f16;
typedef _Float16 f16x8 __attribute__((ext_vector_type(8)));
typedef _Float16 f16x4 __attribute__((ext_vector_type(4)));
typedef float f32x4 __attribute__((ext_vector_type(4)));

namespace {
constexpr int kB = 32, kD = 512, kN = 1024, kF = 256;
constexpr float kScale = 0.04419417382415922f;   // 1/sqrt(512)
constexpr float kLogMarg = -6.931471805599453f;  // -log(1024)
constexpr float kMarg = 1.f / 1024.f;            // 1/n
constexpr float kPScale = 16384.f;               // 2^14: lift pi into f16 range
constexpr float kPInv = 1.f / 16384.f;
}

// global -> LDS direct DMA, 16B per lane. LDS dest is wave-uniform base +
// lane*16 (hardware); global src is per-lane.
__device__ __forceinline__ void gload16(const void* g, void* l) {
  __builtin_amdgcn_global_load_lds(
      (const __attribute__((address_space(1))) void*)g,
      (__attribute__((address_space(3))) void*)l, 16, 0, 0);
}

// ---- K1: val = x[b,c,i] + pos(c,i); emit xfT[lb,c,i] and xf[lb,i,c] (f16) --
__global__ __launch_bounds__(256) void k_prep(
    const float* __restrict__ x, const float* __restrict__ re,
    const float* __restrict__ ce, f16* __restrict__ xf,
    f16* __restrict__ xfT, int b0) {
  __shared__ f16 T[64][68];
  const int lb = blockIdx.z;
  const int i0 = blockIdx.x * 64, c0 = blockIdx.y * 64;
  const int t = threadIdx.x;
  const int il = (t & 15) * 4;  // 0..60
  const int cl = t >> 4;        // 0..15
  const size_t xbase = ((size_t)(b0 + lb) * kD) * kN;
#pragma unroll
  for (int p = 0; p < 4; p++) {
    const int c = c0 + cl + 16 * p;
    const int i = i0 + il;
    const float4 xv = *(const float4*)(x + xbase + (size_t)c * kN + i);
    float4 pv;
    if (c < kF) {  // wave-uniform per block (c0 multiple of 64)
      pv.x = ce[((i + 0) & 31) * kF + c];
      pv.y = ce[((i + 1) & 31) * kF + c];
      pv.z = ce[((i + 2) & 31) * kF + c];
      pv.w = ce[((i + 3) & 31) * kF + c];
    } else {
      const float r = re[(i >> 5) * kF + (c - kF)];
      pv.x = r; pv.y = r; pv.z = r; pv.w = r;
    }
    const f16 h0 = (f16)(xv.x + pv.x), h1 = (f16)(xv.y + pv.y);
    const f16 h2 = (f16)(xv.z + pv.z), h3 = (f16)(xv.w + pv.w);
    f16* dT = xfT + ((size_t)lb * kD + c) * kN + i;
    *(f16x4*)dT = (f16x4){h0, h1, h2, h3};
    T[cl + 16 * p][il + 0] = h0; T[cl + 16 * p][il + 1] = h1;
    T[cl + 16 * p][il + 2] = h2; T[cl + 16 * p][il + 3] = h3;
  }
  __syncthreads();
#pragma unroll
  for (int p = 0; p < 4; p++) {
    const int ir = cl + 16 * p;  // local i
    const int cc = il;           // local c
    const f16 h0 = T[cc + 0][ir], h1 = T[cc + 1][ir];
    const f16 h2 = T[cc + 2][ir], h3 = T[cc + 3][ir];
    f16* dF = xf + ((size_t)lb * kN + i0 + ir) * kD + c0 + cc;
    *(f16x4*)dF = (f16x4){h0, h1, h2, h3};
  }
}

// ---- K2: S16 = f16(kScale * xf @ xf^T), SYMMETRIC: only bx>=by tiles -------
// R2-measured 128x128 config (best for K=512): 4 waves, BK=64, 2-deep dbuf
// (64 KB LDS -> 2 blocks/CU), issue-next-then-compute, one __syncthreads per
// K-step, T1 XCD swizzle + T2 XOR swizzle + gload_lds. Off-diagonal blocks
// ALSO write the mirror tile S[j,i] (f16x4 stores, 128B/row coalesced) and
// its row-partials = this tile's COLUMN sums (reuse the same exp(h) values).
// Coverage: segments C>=R from originals, C<R from mirrors (complete,
// disjoint). 36/64 blocks -> 56% of the FLOPs.
__global__ __launch_bounds__(256) void k_gemm_s(
    const f16* __restrict__ xf, f16* __restrict__ S16,
    float* __restrict__ rp) {
  __shared__ char sm[65536];  // buf0: A[0:16K) B[16K:32K); buf1: +32K
  const int nwg = (int)(gridDim.x * gridDim.z);  // 36*g
  const int lin = (int)(blockIdx.x + gridDim.x * blockIdx.z);
  const int wid = (lin & 7) * (nwg >> 3) + (lin >> 3);
  const int bz = wid / 36;
  int qq = wid - bz * 36;
  int by = 0;
  while (qq >= 8 - by) { qq -= 8 - by; by++; }  // triangle decode
  const int bx = by + qq;                        // bx >= by

  const int lb = bz;
  const int i0 = by * 128, j0 = bx * 128;
  const char* base = (const char*)(xf + (size_t)lb * kN * kD);
  const int t = threadIdx.x;
  const int w = t >> 6, lane = t & 63;
  const int m_off = (w >> 1) * 64, n_off = (w & 1) * 64;
  const int quad = lane >> 4, l15 = lane & 15;
  const int swz = (l15 & 7) << 4;

  // staging: 4 chunks x (4 waves x 1KB). linear LDS off = p*4096+w*1024+lane*16
  int srcA[4], srcB[4], ldsw[4];
#pragma unroll
  for (int p = 0; p < 4; p++) {
    const int off = p * 4096 + w * 1024 + lane * 16;
    const int r = off >> 7;                       // tile row 0..127
    const int cb = (off & 127) ^ ((r & 7) << 4);  // inverse-swizzled src col
    srcA[p] = (i0 + r) * (kD * 2) + cb;           // row stride 1024 B
    srcB[p] = (j0 + r) * (kD * 2) + cb;
    ldsw[p] = p * 4096 + w * 1024;                // wave-uniform LDS base
  }

  f32x4 acc[4][4];
#pragma unroll
  for (int a = 0; a < 4; a++)
#pragma unroll
    for (int b = 0; b < 4; b++) acc[a][b] = (f32x4){0.f, 0.f, 0.f, 0.f};

  // prologue: stage K-tile 0 into buf0
#pragma unroll
  for (int p = 0; p < 4; p++) gload16(base + srcA[p], sm + ldsw[p]);
#pragma unroll
  for (int p = 0; p < 4; p++) gload16(base + srcB[p], sm + 16384 + ldsw[p]);
  __syncthreads();

#pragma unroll
  for (int tt = 0; tt < 8; tt++) {  // 8 K-tiles of 64 f16 (128 B)
    const int cur = tt & 1, nxt = cur ^ 1;
    if (tt + 1 < 8) {  // issue next tile's loads FIRST (overlap with compute)
      const int k0b = (tt + 1) * 128;
#pragma unroll
      for (int p = 0; p < 4; p++)
        gload16(base + srcA[p] + k0b, sm + (nxt << 15) + ldsw[p]);
#pragma unroll
      for (int p = 0; p < 4; p++)
        gload16(base + srcB[p] + k0b, sm + (nxt << 15) + 16384 + ldsw[p]);
    }
    const char* bA = sm + (cur << 15);
    const char* bB = bA + 16384;
#pragma unroll
    for (int kk = 0; kk < 2; kk++) {
      f16x8 af[4], bf[4];
#pragma unroll
      for (int q = 0; q < 4; q++)
        af[q] = *(const f16x8*)(bA + (m_off + 16 * q + l15) * 128 +
                                ((kk * 64 + quad * 16) ^ swz));
#pragma unroll
      for (int q = 0; q < 4; q++)
        bf[q] = *(const f16x8*)(bB + (n_off + 16 * q + l15) * 128 +
                                ((kk * 64 + quad * 16) ^ swz));
#pragma unroll
      for (int qa = 0; qa < 4; qa++)
#pragma unroll
        for (int qb = 0; qb < 4; qb++)
          acc[qa][qb] = __builtin_amdgcn_mfma_f32_16x16x32_f16(
              af[qa], bf[qb], acc[qa][qb], 0, 0, 0);
    }
    __syncthreads();  // drains vmcnt (next tile ready) + protects cur reuse
  }

  f16* Sb = S16 + (size_t)lb * kN * kN;
  const int jt2 = bx * 2 + (w & 1);
  float* rpb = rp + ((size_t)lb * 16 + jt2) * kN + i0 + m_off;
  const bool offd = (bx != by);
  float cs[4] = {0.f, 0.f, 0.f, 0.f};  // column partials (mirror rows)
#pragma unroll
  for (int qa = 0; qa < 4; qa++) {
    const int i = i0 + m_off + 16 * qa + quad * 4;
    float rs[4] = {0.f, 0.f, 0.f, 0.f};
#pragma unroll
    for (int qb = 0; qb < 4; qb++) {
      const int j = j0 + n_off + 16 * qb + l15;
      f16 h4[4];
#pragma unroll
      for (int r = 0; r < 4; r++) {
        const f16 h = (f16)(acc[qa][qb][r] * kScale);
        Sb[(size_t)(i + r) * kN + j] = h;
        h4[r] = h;
        const float e = __expf((float)h);
        rs[r] += e;
        cs[qb] += e;
      }
      if (offd)  // mirror: S[j, i..i+3], 4 consecutive cols -> f16x4 store
        *(f16x4*)(Sb + (size_t)j * kN + i) = (f16x4){h4[0], h4[1], h4[2], h4[3]};
    }
#pragma unroll
    for (int r = 0; r < 4; r++) {
      float s = rs[r];
      s += __shfl_xor(s, 1);
      s += __shfl_xor(s, 2);
      s += __shfl_xor(s, 4);
      s += __shfl_xor(s, 8);
      if (l15 == 0) rpb[16 * qa + 4 * quad + r] = s;
    }
  }
  if (offd) {  // mirror row-partials = column sums; segment = i-range
    float* rpm = rp + ((size_t)lb * 16 + (by * 2 + (w >> 1))) * kN;
#pragma unroll
    for (int qb = 0; qb < 4; qb++) {
      float s = cs[qb];
      s += __shfl_xor(s, 16);  // reduce over the 4 quads
      s += __shfl_xor(s, 32);
      if (quad == 0) rpm[j0 + n_off + 16 * qb + l15] = s;
    }
  }
}

// ---- K3: u[lb,i] = -log(n) - log(sum of 16 row partials) -------------------
__global__ __launch_bounds__(256) void k_u(
    const float* __restrict__ rp, float* __restrict__ u) {
  const int lb = blockIdx.y;
  const int i = blockIdx.x * 256 + threadIdx.x;
  const float* r = rp + (size_t)lb * 16 * kN + i;
  float s = 0.f;
#pragma unroll
  for (int t = 0; t < 16; t++) s += r[(size_t)t * kN];
  u[lb * kN + i] = kLogMarg - __logf(s);
}

// ---- K4: column partial sums of exp(S16 + u_i), row-major vectorized -------
// Each thread owns 4 consecutive columns, loops 64 rows: f16x4 coalesced
// reads (512 B per wave-instr), uniform u[r] scalar loads.
__global__ __launch_bounds__(256) void k_cs(
    const f16* __restrict__ S16, const float* __restrict__ u,
    float* __restrict__ cp) {
  const int lb = blockIdx.z;
  const int seg = blockIdx.y;
  const int j = threadIdx.x * 4;
  const f16* Sb = S16 + (size_t)lb * kN * kN + (size_t)(seg * 64) * kN + j;
  const float* ub = u + lb * kN + seg * 64;
  float s0 = 0.f, s1 = 0.f, s2 = 0.f, s3 = 0.f;
#pragma unroll 8
  for (int r = 0; r < 64; r++) {
    const f16x4 v = *(const f16x4*)(Sb + (size_t)r * kN);
    const float ur = ub[r];
    s0 += __expf((float)v[0] + ur);
    s1 += __expf((float)v[1] + ur);
    s2 += __expf((float)v[2] + ur);
    s3 += __expf((float)v[3] + ur);
  }
  float4 o = {s0, s1, s2, s3};
  *(float4*)(cp + ((size_t)lb * 16 + seg) * kN + j) = o;
}

// ---- K5: ev[lb,j] = exp(v_j) = (1/n) / colsum_j ----------------------------
__global__ __launch_bounds__(256) void k_v(
    const float* __restrict__ cp, float* __restrict__ ev) {
  const int lb = blockIdx.y;
  const int j = blockIdx.x * 256 + threadIdx.x;
  const float* c = cp + (size_t)lb * 16 * kN + j;
  float s = 0.f;
#pragma unroll
  for (int r = 0; r < 16; r++) s += c[(size_t)r * kN];
  ev[lb * kN + j] = kMarg / s;
}

// ---- K6: t16[i,j] = f16(2^14 * exp(S16 + u_i) * ev_j)  (= 2^14 * pi_ij) ----
__global__ __launch_bounds__(256) void k_pt(
    const f16* __restrict__ S16, const float* __restrict__ u,
    const float* __restrict__ ev, f16* __restrict__ t16) {
  const int row = blockIdx.x;  // lb*kN + i
  const float ui = u[row];
  const f16* Sr = S16 + (size_t)row * kN;
  const float* evb = ev + (size_t)(row >> 10) * kN;
  f16* Tr = t16 + (size_t)row * kN;
  const int j = threadIdx.x * 4;
  const f16x4 s = *(const f16x4*)(Sr + j);
  const float4 e = *(const float4*)(evb + j);
  f16x4 o;
  o[0] = (f16)(__expf((float)s[0] + ui) * e.x * kPScale);
  o[1] = (f16)(__expf((float)s[1] + ui) * e.y * kPScale);
  o[2] = (f16)(__expf((float)s[2] + ui) * e.z * kPScale);
  o[3] = (f16)(__expf((float)s[3] + ui) * e.w * kPScale);
  *(f16x4*)(Tr + j) = o;
}

// Per-phase fragment read + MFMA cluster (gemm_o).
#define AF_READ(q)                                                          \
  _Pragma("unroll")                                                         \
  for (int pa = 0; pa < 2; pa++)                                            \
    _Pragma("unroll")                                                       \
    for (int kk = 0; kk < 2; kk++)                                          \
      af[pa][kk] = *(const f16x8*)(bA + (m_off + 32*(q) + 16*pa + l15)*128  \
                                   + ((kk*64 + quad*16) ^ swz));

#define MFMA_PH(q)                                                          \
  __builtin_amdgcn_s_setprio(1);                                            \
  _Pragma("unroll")                                                         \
  for (int pa = 0; pa < 2; pa++)                                            \
    _Pragma("unroll")                                                       \
    for (int qb = 0; qb < 4; qb++)                                          \
      _Pragma("unroll")                                                     \
      for (int kk = 0; kk < 2; kk++)                                        \
        acc[2*(q)+pa][qb] = __builtin_amdgcn_mfma_f32_16x16x32_f16(         \
            af[pa][kk], bf[qb][kk], acc[2*(q)+pa][qb], 0, 0, 0);            \
  __builtin_amdgcn_s_setprio(0);

// ---- K7: out[b,c,i] = (1/2^14) * sum_j xfT[c,j] * t16[i,j]  (f16 MFMA) -----
// R5-proven split-group deep-lead schedule; K=1024 (16 tiles), 2048B rows.
__global__ __launch_bounds__(512) void k_gemm_o(
    const f16* __restrict__ xfT, const f16* __restrict__ P,
    float* __restrict__ out, int b0) {
  __shared__ char sm[131072];
  const int nwg = (int)(gridDim.x * gridDim.y * gridDim.z);  // 8*g, %8==0
  const int lin = (int)(blockIdx.x +
                        gridDim.x * (blockIdx.y + gridDim.y * blockIdx.z));
  const int wid = (lin & 7) * (nwg >> 3) + (lin >> 3);
  const int bx = wid & 3, by = (wid >> 2) & 1, bz = wid >> 3;

  const int lb = bz;
  const int i0 = bx * 256, c0 = by * 256;
  const char* Ab = (const char*)(xfT + (size_t)lb * kD * kN);  // rows c
  const char* Bb = (const char*)(P + (size_t)lb * kN * kN);    // rows i
  const int t = threadIdx.x;
  const int w = t >> 6, lane = t & 63;
  const int wm = w >> 2, wn = w & 3;
  const int m_off = wm * 128, n_off = wn * 64;
  const int quad = lane >> 4, l15 = lane & 15;
  const int swz = (l15 & 7) << 4;

  int srcA[4], srcB[4], ldsw[4];
#pragma unroll
  for (int p = 0; p < 4; p++) {
    const int off = p * 8192 + t * 16;
    const int r = off >> 7;
    const int cb = (off & 127) ^ ((r & 7) << 4);
    srcA[p] = (c0 + r) * (kN * 2) + cb;  // row stride 2048 B
    srcB[p] = (i0 + r) * (kN * 2) + cb;
    ldsw[p] = p * 8192 + w * 1024;
  }

  // prologue: B(0)x4, A{0,2}(0), A{1,3}(0), B(1)x4 -> vmcnt(6) proves
  // B(0)+A{0,2}(0); A{1,3}(0)+B(1) stay in flight.
#pragma unroll
  for (int p = 0; p < 4; p++) gload16(Bb + srcB[p], sm + 65536 + ldsw[p]);
  gload16(Ab + srcA[0], sm + ldsw[0]);
  gload16(Ab + srcA[2], sm + ldsw[2]);
  gload16(Ab + srcA[1], sm + ldsw[1]);
  gload16(Ab + srcA[3], sm + ldsw[3]);
#pragma unroll
  for (int p = 0; p < 4; p++)
    gload16(Bb + srcB[p] + 128, sm + 65536 + 32768 + ldsw[p]);
  f32x4 acc[8][4];
#pragma unroll
  for (int a = 0; a < 8; a++)
#pragma unroll
    for (int b = 0; b < 4; b++) acc[a][b] = (f32x4){0.f, 0.f, 0.f, 0.f};
  asm volatile("s_waitcnt vmcnt(6)" ::: "memory");
  __builtin_amdgcn_s_barrier();
  __builtin_amdgcn_sched_barrier(0);

#pragma unroll
  for (int tt = 0; tt < 16; tt++) {
    const int cur = tt & 1, nxt = cur ^ 1;
    const char* bA = sm + cur * 32768;
    const char* bB = sm + 65536 + cur * 32768;
    char* wA = sm + nxt * 32768;
    char* wB = sm + 65536 + cur * 32768;  // B(t+2) reuses slot of B(t)
    const int kA = (tt + 1) * 128, kBB = (tt + 2) * 128;
    f16x8 bf[4][2], af[2][2];
    // P0: all B + A-phase0 fragments; drain; barrier; MFMA0
#pragma unroll
    for (int qb = 0; qb < 4; qb++)
#pragma unroll
      for (int kk = 0; kk < 2; kk++)
        bf[qb][kk] = *(const f16x8*)(bB + (n_off + 16 * qb + l15) * 128 +
                                     ((kk * 64 + quad * 16) ^ swz));
    AF_READ(0)
    asm volatile("s_waitcnt lgkmcnt(0)" ::: "memory");
    __builtin_amdgcn_sched_barrier(0);
    __builtin_amdgcn_s_barrier();
    MFMA_PH(0)
    // P1: issue A chunks 0,2 of t+1
    if (tt + 1 < 16) {
      gload16(Ab + srcA[0] + kA, wA + ldsw[0]);
      gload16(Ab + srcA[2] + kA, wA + ldsw[2]);
    }
    AF_READ(1)
    __builtin_amdgcn_s_barrier();
    MFMA_PH(1)
    if (tt == 15) { asm volatile("s_waitcnt vmcnt(0)" ::: "memory"); }
    else          { asm volatile("s_waitcnt vmcnt(6)" ::: "memory"); }
    __builtin_amdgcn_s_barrier();
    __builtin_amdgcn_sched_barrier(0);
    // P2
    AF_READ(2)
    __builtin_amdgcn_s_barrier();
    MFMA_PH(2)
    // P3: issue A chunks 1,3 of t+1 and all B of t+2
    if (tt + 1 < 16) {
      gload16(Ab + srcA[1] + kA, wA + ldsw[1]);
      gload16(Ab + srcA[3] + kA, wA + ldsw[3]);
    }
    if (tt + 2 < 16) {
#pragma unroll
      for (int p = 0; p < 4; p++)
        gload16(Bb + srcB[p] + kBB, wB + ldsw[p]);
    }
    AF_READ(3)
    __builtin_amdgcn_s_barrier();
    MFMA_PH(3)
    if (tt + 2 < 16)      { asm volatile("s_waitcnt vmcnt(6)" ::: "memory"); }
    else if (tt + 1 < 16) { asm volatile("s_waitcnt vmcnt(2)" ::: "memory"); }
    __builtin_amdgcn_s_barrier();
    __builtin_amdgcn_sched_barrier(0);
  }

  float* ob = out + ((size_t)(b0 + lb) * kD) * kN;
#pragma unroll
  for (int qa = 0; qa < 8; qa++) {
    const int c = c0 + m_off + 16 * qa + quad * 4;
#pragma unroll
    for (int qb = 0; qb < 4; qb++) {
      const int i = i0 + n_off + 16 * qb + l15;
#pragma unroll
      for (int r = 0; r < 4; r++)
        ob[(size_t)(c + r) * kN + i] = acc[qa][qb][r] * kPInv;
    }
  }
}

extern "C" void kernel_launch(void* const* d_in, const int* in_sizes, int n_in,
                              void* d_out, int out_size, void* d_ws, size_t ws_size,
                              hipStream_t stream) {
  const float* x = (const float*)d_in[0];
  const float* re = (const float*)d_in[1];
  const float* ce = (const float*)d_in[2];
  float* out = (float*)d_out;

  // ws per batch: S16 2MB + xf 1MB + xfT 1MB + t16 2MB + u 4KB + ev 4KB
  //             + rp 64KB + cp 64KB = ~6.13 MB. ws=256MiB -> G=32, ONE chunk.
  char* wsb = (char*)d_ws;
  const size_t perb = 2097152ull + 1048576 + 1048576 + 2097152 +
                      4096 + 4096 + 65536 + 65536;
  int G = (int)(ws_size / perb);
  if (G >= 32) G = 32;
  else if (G >= 16) G = 16;
  else if (G >= 8) G = 8;
  else if (G >= 4) G = 4;
  else if (G < 1) G = 1;
  f16* S16 = (f16*)wsb;
  f16* xf = (f16*)(wsb + (size_t)G * 2097152);
  f16* xfT = (f16*)((char*)xf + (size_t)G * 1048576);
  f16* t16 = (f16*)((char*)xfT + (size_t)G * 1048576);
  float* u = (float*)((char*)t16 + (size_t)G * 2097152);
  float* ev = u + (size_t)G * kN;
  float* rp = ev + (size_t)G * kN;            // [G][16][kN]
  float* cp = rp + (size_t)G * 16 * kN;       // [G][16][kN]

  for (int b0 = 0; b0 < kB; b0 += G) {
    const int g = (kB - b0 < G) ? (kB - b0) : G;
    k_prep<<<dim3(16, 8, g), 256, 0, stream>>>(x, re, ce, xf, xfT, b0);
    k_gemm_s<<<dim3(36, 1, g), 256, 0, stream>>>(xf, S16, rp);
    k_u<<<dim3(4, g), 256, 0, stream>>>(rp, u);
    k_cs<<<dim3(1, 16, g), 256, 0, stream>>>(S16, u, cp);
    k_v<<<dim3(4, g), 256, 0, stream>>>(cp, ev);
    k_pt<<<g * kN, 256, 0, stream>>>(S16, u, ev, t16);
    k_gemm_o<<<dim3(4, 2, g), 512, 0, stream>>>(xfT, t16, out, b0);
  }
}

// Round 9
// 231.956 us; speedup vs baseline: 1.1119x; 1.0259x over previous
//
#include <hip/hip_runtime.h>
#include <hip/hip_fp16.h>
#include <math.h>

typedef _Float16 f16;
typedef _Float16 f16x8 __attribute__((ext_vector_type(8)));
typedef _Float16 f16x4 __attribute__((ext_vector_type(4)));
typedef float f32x4 __attribute__((ext_vector_type(4)));

namespace {
constexpr int kB = 32, kD = 512, kN = 1024, kF = 256;
constexpr float kScale = 0.04419417382415922f;   // 1/sqrt(512)
constexpr float kLogMarg = -6.931471805599453f;  // -log(1024)
constexpr float kMarg = 1.f / 1024.f;            // 1/n
constexpr float kPScale = 16384.f;               // 2^14: lift pi into f16 range
constexpr float kPInv = 1.f / 16384.f;
}

// global -> LDS direct DMA, 16B per lane. LDS dest is wave-uniform base +
// lane*16 (hardware); global src is per-lane.
__device__ __forceinline__ void gload16(const void* g, void* l) {
  __builtin_amdgcn_global_load_lds(
      (const __attribute__((address_space(1))) void*)g,
      (__attribute__((address_space(3))) void*)l, 16, 0, 0);
}

// ---- K1: val = x[b,c,i] + pos(c,i); emit xfT[lb,c,i] and xf[lb,i,c] (f16) --
__global__ __launch_bounds__(256) void k_prep(
    const float* __restrict__ x, const float* __restrict__ re,
    const float* __restrict__ ce, f16* __restrict__ xf,
    f16* __restrict__ xfT, int b0) {
  __shared__ f16 T[64][68];
  const int lb = blockIdx.z;
  const int i0 = blockIdx.x * 64, c0 = blockIdx.y * 64;
  const int t = threadIdx.x;
  const int il = (t & 15) * 4;  // 0..60
  const int cl = t >> 4;        // 0..15
  const size_t xbase = ((size_t)(b0 + lb) * kD) * kN;
#pragma unroll
  for (int p = 0; p < 4; p++) {
    const int c = c0 + cl + 16 * p;
    const int i = i0 + il;
    const float4 xv = *(const float4*)(x + xbase + (size_t)c * kN + i);
    float4 pv;
    if (c < kF) {  // wave-uniform per block (c0 multiple of 64)
      pv.x = ce[((i + 0) & 31) * kF + c];
      pv.y = ce[((i + 1) & 31) * kF + c];
      pv.z = ce[((i + 2) & 31) * kF + c];
      pv.w = ce[((i + 3) & 31) * kF + c];
    } else {
      const float r = re[(i >> 5) * kF + (c - kF)];
      pv.x = r; pv.y = r; pv.z = r; pv.w = r;
    }
    const f16 h0 = (f16)(xv.x + pv.x), h1 = (f16)(xv.y + pv.y);
    const f16 h2 = (f16)(xv.z + pv.z), h3 = (f16)(xv.w + pv.w);
    f16* dT = xfT + ((size_t)lb * kD + c) * kN + i;
    *(f16x4*)dT = (f16x4){h0, h1, h2, h3};
    T[cl + 16 * p][il + 0] = h0; T[cl + 16 * p][il + 1] = h1;
    T[cl + 16 * p][il + 2] = h2; T[cl + 16 * p][il + 3] = h3;
  }
  __syncthreads();
#pragma unroll
  for (int p = 0; p < 4; p++) {
    const int ir = cl + 16 * p;  // local i
    const int cc = il;           // local c
    const f16 h0 = T[cc + 0][ir], h1 = T[cc + 1][ir];
    const f16 h2 = T[cc + 2][ir], h3 = T[cc + 3][ir];
    f16* dF = xf + ((size_t)lb * kN + i0 + ir) * kD + c0 + cc;
    *(f16x4*)dF = (f16x4){h0, h1, h2, h3};
  }
}

// ---- K2: S16 = f16(kScale * xf @ xf^T), SYMMETRIC: only bx>=by tiles -------
// R2-measured 128x128 config, 2-deep dbuf, T1+T2 swizzles, gload_lds.
// Off-diagonal blocks also write the mirror tile and its row-partials
// (= this tile's column sums, reusing the same exp(h) values).
__global__ __launch_bounds__(256) void k_gemm_s(
    const f16* __restrict__ xf, f16* __restrict__ S16,
    float* __restrict__ rp) {
  __shared__ char sm[65536];  // buf0: A[0:16K) B[16K:32K); buf1: +32K
  const int nwg = (int)(gridDim.x * gridDim.z);  // 36*g
  const int lin = (int)(blockIdx.x + gridDim.x * blockIdx.z);
  const int wid = (lin & 7) * (nwg >> 3) + (lin >> 3);
  const int bz = wid / 36;
  int qq = wid - bz * 36;
  int by = 0;
  while (qq >= 8 - by) { qq -= 8 - by; by++; }  // triangle decode
  const int bx = by + qq;                        // bx >= by

  const int lb = bz;
  const int i0 = by * 128, j0 = bx * 128;
  const char* base = (const char*)(xf + (size_t)lb * kN * kD);
  const int t = threadIdx.x;
  const int w = t >> 6, lane = t & 63;
  const int m_off = (w >> 1) * 64, n_off = (w & 1) * 64;
  const int quad = lane >> 4, l15 = lane & 15;
  const int swz = (l15 & 7) << 4;

  // staging: 4 chunks x (4 waves x 1KB). linear LDS off = p*4096+w*1024+lane*16
  int srcA[4], srcB[4], ldsw[4];
#pragma unroll
  for (int p = 0; p < 4; p++) {
    const int off = p * 4096 + w * 1024 + lane * 16;
    const int r = off >> 7;                       // tile row 0..127
    const int cb = (off & 127) ^ ((r & 7) << 4);  // inverse-swizzled src col
    srcA[p] = (i0 + r) * (kD * 2) + cb;           // row stride 1024 B
    srcB[p] = (j0 + r) * (kD * 2) + cb;
    ldsw[p] = p * 4096 + w * 1024;                // wave-uniform LDS base
  }

  f32x4 acc[4][4];
#pragma unroll
  for (int a = 0; a < 4; a++)
#pragma unroll
    for (int b = 0; b < 4; b++) acc[a][b] = (f32x4){0.f, 0.f, 0.f, 0.f};

  // prologue: stage K-tile 0 into buf0
#pragma unroll
  for (int p = 0; p < 4; p++) gload16(base + srcA[p], sm + ldsw[p]);
#pragma unroll
  for (int p = 0; p < 4; p++) gload16(base + srcB[p], sm + 16384 + ldsw[p]);
  __syncthreads();

#pragma unroll
  for (int tt = 0; tt < 8; tt++) {  // 8 K-tiles of 64 f16 (128 B)
    const int cur = tt & 1, nxt = cur ^ 1;
    if (tt + 1 < 8) {  // issue next tile's loads FIRST (overlap with compute)
      const int k0b = (tt + 1) * 128;
#pragma unroll
      for (int p = 0; p < 4; p++)
        gload16(base + srcA[p] + k0b, sm + (nxt << 15) + ldsw[p]);
#pragma unroll
      for (int p = 0; p < 4; p++)
        gload16(base + srcB[p] + k0b, sm + (nxt << 15) + 16384 + ldsw[p]);
    }
    const char* bA = sm + (cur << 15);
    const char* bB = bA + 16384;
#pragma unroll
    for (int kk = 0; kk < 2; kk++) {
      f16x8 af[4], bf[4];
#pragma unroll
      for (int q = 0; q < 4; q++)
        af[q] = *(const f16x8*)(bA + (m_off + 16 * q + l15) * 128 +
                                ((kk * 64 + quad * 16) ^ swz));
#pragma unroll
      for (int q = 0; q < 4; q++)
        bf[q] = *(const f16x8*)(bB + (n_off + 16 * q + l15) * 128 +
                                ((kk * 64 + quad * 16) ^ swz));
#pragma unroll
      for (int qa = 0; qa < 4; qa++)
#pragma unroll
        for (int qb = 0; qb < 4; qb++)
          acc[qa][qb] = __builtin_amdgcn_mfma_f32_16x16x32_f16(
              af[qa], bf[qb], acc[qa][qb], 0, 0, 0);
    }
    __syncthreads();  // drains vmcnt (next tile ready) + protects cur reuse
  }

  f16* Sb = S16 + (size_t)lb * kN * kN;
  const int jt2 = bx * 2 + (w & 1);
  float* rpb = rp + ((size_t)lb * 16 + jt2) * kN + i0 + m_off;
  const bool offd = (bx != by);
  float cs[4] = {0.f, 0.f, 0.f, 0.f};  // column partials (mirror rows)
#pragma unroll
  for (int qa = 0; qa < 4; qa++) {
    const int i = i0 + m_off + 16 * qa + quad * 4;
    float rs[4] = {0.f, 0.f, 0.f, 0.f};
#pragma unroll
    for (int qb = 0; qb < 4; qb++) {
      const int j = j0 + n_off + 16 * qb + l15;
      f16 h4[4];
#pragma unroll
      for (int r = 0; r < 4; r++) {
        const f16 h = (f16)(acc[qa][qb][r] * kScale);
        Sb[(size_t)(i + r) * kN + j] = h;
        h4[r] = h;
        const float e = __expf((float)h);
        rs[r] += e;
        cs[qb] += e;
      }
      if (offd)  // mirror: S[j, i..i+3], 4 consecutive cols -> f16x4 store
        *(f16x4*)(Sb + (size_t)j * kN + i) = (f16x4){h4[0], h4[1], h4[2], h4[3]};
    }
#pragma unroll
    for (int r = 0; r < 4; r++) {
      float s = rs[r];
      s += __shfl_xor(s, 1);
      s += __shfl_xor(s, 2);
      s += __shfl_xor(s, 4);
      s += __shfl_xor(s, 8);
      if (l15 == 0) rpb[16 * qa + 4 * quad + r] = s;
    }
  }
  if (offd) {  // mirror row-partials = column sums; segment = i-range
    float* rpm = rp + ((size_t)lb * 16 + (by * 2 + (w >> 1))) * kN;
#pragma unroll
    for (int qb = 0; qb < 4; qb++) {
      float s = cs[qb];
      s += __shfl_xor(s, 16);  // reduce over the 4 quads
      s += __shfl_xor(s, 32);
      if (quad == 0) rpm[j0 + n_off + 16 * qb + l15] = s;
    }
  }
}

// ---- K3: fused u + column partial sums ------------------------------------
// Threads <64 first compute u for this seg's 64 rows (u = -log(n) -
// log(sum of 16 row partials), SAME summation order as old k_u -> bit-
// identical), stash in LDS + store to global for k_pt. Then all 256 threads
// accumulate column partials of exp(S16 + u_i) over the 64 rows (f16x4
// coalesced reads).
__global__ __launch_bounds__(256) void k_cs(
    const f16* __restrict__ S16, const float* __restrict__ rp,
    float* __restrict__ u, float* __restrict__ cp) {
  __shared__ float us[64];
  const int lb = blockIdx.z;
  const int seg = blockIdx.y;
  const int tid = threadIdx.x;
  if (tid < 64) {
    const float* r = rp + (size_t)lb * 16 * kN + seg * 64 + tid;
    float s = 0.f;
#pragma unroll
    for (int t = 0; t < 16; t++) s += r[(size_t)t * kN];
    const float uu = kLogMarg - __logf(s);
    us[tid] = uu;
    u[lb * kN + seg * 64 + tid] = uu;
  }
  __syncthreads();
  const int j = tid * 4;
  const f16* Sb = S16 + (size_t)lb * kN * kN + (size_t)(seg * 64) * kN + j;
  float s0 = 0.f, s1 = 0.f, s2 = 0.f, s3 = 0.f;
#pragma unroll 8
  for (int r = 0; r < 64; r++) {
    const f16x4 v = *(const f16x4*)(Sb + (size_t)r * kN);
    const float ur = us[r];
    s0 += __expf((float)v[0] + ur);
    s1 += __expf((float)v[1] + ur);
    s2 += __expf((float)v[2] + ur);
    s3 += __expf((float)v[3] + ur);
  }
  float4 o = {s0, s1, s2, s3};
  *(float4*)(cp + ((size_t)lb * 16 + seg) * kN + j) = o;
}

// ---- K4: fused ev + transport tile: t16 = f16(2^14*exp(S16+u_i)*ev_j) ------
// 64-row x 1024-col blocks (grid 16 x g). Each thread owns 4 fixed columns:
// computes ev_j = (1/n)/colsum_j once into registers (SAME summation order
// as old k_v), loads the seg's u into LDS, then streams 64 rows with the
// exact multiply order of the old k_pt: (exp(s+u) * ev) * 2^14.
__global__ __launch_bounds__(256) void k_pt(
    const f16* __restrict__ S16, const float* __restrict__ u,
    const float* __restrict__ cp, f16* __restrict__ t16) {
  __shared__ float us[64];
  const int seg = blockIdx.x;  // 0..15
  const int lb = blockIdx.y;
  const int tid = threadIdx.x;
  const int j = tid * 4;
  const float* c = cp + (size_t)lb * 16 * kN + j;
  float s0 = 0.f, s1 = 0.f, s2 = 0.f, s3 = 0.f;
#pragma unroll
  for (int r = 0; r < 16; r++) {
    const float4 v = *(const float4*)(c + (size_t)r * kN);
    s0 += v.x; s1 += v.y; s2 += v.z; s3 += v.w;
  }
  const float e0 = kMarg / s0, e1 = kMarg / s1;
  const float e2 = kMarg / s2, e3 = kMarg / s3;
  if (tid < 64) us[tid] = u[lb * kN + seg * 64 + tid];
  __syncthreads();
  const f16* Sb = S16 + (size_t)lb * kN * kN + (size_t)(seg * 64) * kN + j;
  f16* Tb = t16 + (size_t)lb * kN * kN + (size_t)(seg * 64) * kN + j;
#pragma unroll 4
  for (int r = 0; r < 64; r++) {
    const f16x4 v = *(const f16x4*)(Sb + (size_t)r * kN);
    const float ur = us[r];
    f16x4 o;
    o[0] = (f16)(__expf((float)v[0] + ur) * e0 * kPScale);
    o[1] = (f16)(__expf((float)v[1] + ur) * e1 * kPScale);
    o[2] = (f16)(__expf((float)v[2] + ur) * e2 * kPScale);
    o[3] = (f16)(__expf((float)v[3] + ur) * e3 * kPScale);
    *(f16x4*)(Tb + (size_t)r * kN) = o;
  }
}

// Per-phase fragment read + MFMA cluster (gemm_o).
#define AF_READ(q)                                                          \
  _Pragma("unroll")                                                         \
  for (int pa = 0; pa < 2; pa++)                                            \
    _Pragma("unroll")                                                       \
    for (int kk = 0; kk < 2; kk++)                                          \
      af[pa][kk] = *(const f16x8*)(bA + (m_off + 32*(q) + 16*pa + l15)*128  \
                                   + ((kk*64 + quad*16) ^ swz));

#define MFMA_PH(q)                                                          \
  __builtin_amdgcn_s_setprio(1);                                            \
  _Pragma("unroll")                                                         \
  for (int pa = 0; pa < 2; pa++)                                            \
    _Pragma("unroll")                                                       \
    for (int qb = 0; qb < 4; qb++)                                          \
      _Pragma("unroll")                                                     \
      for (int kk = 0; kk < 2; kk++)                                        \
        acc[2*(q)+pa][qb] = __builtin_amdgcn_mfma_f32_16x16x32_f16(         \
            af[pa][kk], bf[qb][kk], acc[2*(q)+pa][qb], 0, 0, 0);            \
  __builtin_amdgcn_s_setprio(0);

// ---- K5: out[b,c,i] = (1/2^14) * sum_j xfT[c,j] * t16[i,j]  (f16 MFMA) -----
// R5-proven split-group deep-lead schedule; K=1024 (16 tiles), 2048B rows.
__global__ __launch_bounds__(512) void k_gemm_o(
    const f16* __restrict__ xfT, const f16* __restrict__ P,
    float* __restrict__ out, int b0) {
  __shared__ char sm[131072];
  const int nwg = (int)(gridDim.x * gridDim.y * gridDim.z);  // 8*g, %8==0
  const int lin = (int)(blockIdx.x +
                        gridDim.x * (blockIdx.y + gridDim.y * blockIdx.z));
  const int wid = (lin & 7) * (nwg >> 3) + (lin >> 3);
  const int bx = wid & 3, by = (wid >> 2) & 1, bz = wid >> 3;

  const int lb = bz;
  const int i0 = bx * 256, c0 = by * 256;
  const char* Ab = (const char*)(xfT + (size_t)lb * kD * kN);  // rows c
  const char* Bb = (const char*)(P + (size_t)lb * kN * kN);    // rows i
  const int t = threadIdx.x;
  const int w = t >> 6, lane = t & 63;
  const int wm = w >> 2, wn = w & 3;
  const int m_off = wm * 128, n_off = wn * 64;
  const int quad = lane >> 4, l15 = lane & 15;
  const int swz = (l15 & 7) << 4;

  int srcA[4], srcB[4], ldsw[4];
#pragma unroll
  for (int p = 0; p < 4; p++) {
    const int off = p * 8192 + t * 16;
    const int r = off >> 7;
    const int cb = (off & 127) ^ ((r & 7) << 4);
    srcA[p] = (c0 + r) * (kN * 2) + cb;  // row stride 2048 B
    srcB[p] = (i0 + r) * (kN * 2) + cb;
    ldsw[p] = p * 8192 + w * 1024;
  }

  // prologue: B(0)x4, A{0,2}(0), A{1,3}(0), B(1)x4 -> vmcnt(6) proves
  // B(0)+A{0,2}(0); A{1,3}(0)+B(1) stay in flight.
#pragma unroll
  for (int p = 0; p < 4; p++) gload16(Bb + srcB[p], sm + 65536 + ldsw[p]);
  gload16(Ab + srcA[0], sm + ldsw[0]);
  gload16(Ab + srcA[2], sm + ldsw[2]);
  gload16(Ab + srcA[1], sm + ldsw[1]);
  gload16(Ab + srcA[3], sm + ldsw[3]);
#pragma unroll
  for (int p = 0; p < 4; p++)
    gload16(Bb + srcB[p] + 128, sm + 65536 + 32768 + ldsw[p]);
  f32x4 acc[8][4];
#pragma unroll
  for (int a = 0; a < 8; a++)
#pragma unroll
    for (int b = 0; b < 4; b++) acc[a][b] = (f32x4){0.f, 0.f, 0.f, 0.f};
  asm volatile("s_waitcnt vmcnt(6)" ::: "memory");
  __builtin_amdgcn_s_barrier();
  __builtin_amdgcn_sched_barrier(0);

#pragma unroll
  for (int tt = 0; tt < 16; tt++) {
    const int cur = tt & 1, nxt = cur ^ 1;
    const char* bA = sm + cur * 32768;
    const char* bB = sm + 65536 + cur * 32768;
    char* wA = sm + nxt * 32768;
    char* wB = sm + 65536 + cur * 32768;  // B(t+2) reuses slot of B(t)
    const int kA = (tt + 1) * 128, kBB = (tt + 2) * 128;
    f16x8 bf[4][2], af[2][2];
    // P0: all B + A-phase0 fragments; drain; barrier; MFMA0
#pragma unroll
    for (int qb = 0; qb < 4; qb++)
#pragma unroll
      for (int kk = 0; kk < 2; kk++)
        bf[qb][kk] = *(const f16x8*)(bB + (n_off + 16 * qb + l15) * 128 +
                                     ((kk * 64 + quad * 16) ^ swz));
    AF_READ(0)
    asm volatile("s_waitcnt lgkmcnt(0)" ::: "memory");
    __builtin_amdgcn_sched_barrier(0);
    __builtin_amdgcn_s_barrier();
    MFMA_PH(0)
    // P1: issue A chunks 0,2 of t+1
    if (tt + 1 < 16) {
      gload16(Ab + srcA[0] + kA, wA + ldsw[0]);
      gload16(Ab + srcA[2] + kA, wA + ldsw[2]);
    }
    AF_READ(1)
    __builtin_amdgcn_s_barrier();
    MFMA_PH(1)
    if (tt == 15) { asm volatile("s_waitcnt vmcnt(0)" ::: "memory"); }
    else          { asm volatile("s_waitcnt vmcnt(6)" ::: "memory"); }
    __builtin_amdgcn_s_barrier();
    __builtin_amdgcn_sched_barrier(0);
    // P2
    AF_READ(2)
    __builtin_amdgcn_s_barrier();
    MFMA_PH(2)
    // P3: issue A chunks 1,3 of t+1 and all B of t+2
    if (tt + 1 < 16) {
      gload16(Ab + srcA[1] + kA, wA + ldsw[1]);
      gload16(Ab + srcA[3] + kA, wA + ldsw[3]);
    }
    if (tt + 2 < 16) {
#pragma unroll
      for (int p = 0; p < 4; p++)
        gload16(Bb + srcB[p] + kBB, wB + ldsw[p]);
    }
    AF_READ(3)
    __builtin_amdgcn_s_barrier();
    MFMA_PH(3)
    if (tt + 2 < 16)      { asm volatile("s_waitcnt vmcnt(6)" ::: "memory"); }
    else if (tt + 1 < 16) { asm volatile("s_waitcnt vmcnt(2)" ::: "memory"); }
    __builtin_amdgcn_s_barrier();
    __builtin_amdgcn_sched_barrier(0);
  }

  float* ob = out + ((size_t)(b0 + lb) * kD) * kN;
#pragma unroll
  for (int qa = 0; qa < 8; qa++) {
    const int c = c0 + m_off + 16 * qa + quad * 4;
#pragma unroll
    for (int qb = 0; qb < 4; qb++) {
      const int i = i0 + n_off + 16 * qb + l15;
#pragma unroll
      for (int r = 0; r < 4; r++)
        ob[(size_t)(c + r) * kN + i] = acc[qa][qb][r] * kPInv;
    }
  }
}

extern "C" void kernel_launch(void* const* d_in, const int* in_sizes, int n_in,
                              void* d_out, int out_size, void* d_ws, size_t ws_size,
                              hipStream_t stream) {
  const float* x = (const float*)d_in[0];
  const float* re = (const float*)d_in[1];
  const float* ce = (const float*)d_in[2];
  float* out = (float*)d_out;

  // ws per batch: S16 2MB + xf 1MB + xfT 1MB + t16 2MB + u 4KB
  //             + rp 64KB + cp 64KB = ~6.13 MB. ws=256MiB -> G=32, ONE chunk.
  char* wsb = (char*)d_ws;
  const size_t perb = 2097152ull + 1048576 + 1048576 + 2097152 +
                      4096 + 65536 + 65536;
  int G = (int)(ws_size / perb);
  if (G >= 32) G = 32;
  else if (G >= 16) G = 16;
  else if (G >= 8) G = 8;
  else if (G >= 4) G = 4;
  else if (G < 1) G = 1;
  f16* S16 = (f16*)wsb;
  f16* xf = (f16*)(wsb + (size_t)G * 2097152);
  f16* xfT = (f16*)((char*)xf + (size_t)G * 1048576);
  f16* t16 = (f16*)((char*)xfT + (size_t)G * 1048576);
  float* u = (float*)((char*)t16 + (size_t)G * 2097152);
  float* rp = u + (size_t)G * kN;             // [G][16][kN]
  float* cp = rp + (size_t)G * 16 * kN;       // [G][16][kN]

  for (int b0 = 0; b0 < kB; b0 += G) {
    const int g = (kB - b0 < G) ? (kB - b0) : G;
    k_prep<<<dim3(16, 8, g), 256, 0, stream>>>(x, re, ce, xf, xfT, b0);
    k_gemm_s<<<dim3(36, 1, g), 256, 0, stream>>>(xf, S16, rp);
    k_cs<<<dim3(1, 16, g), 256, 0, stream>>>(S16, rp, u, cp);
    k_pt<<<dim3(16, g), 256, 0, stream>>>(S16, u, cp, t16);
    k_gemm_o<<<dim3(4, 2, g), 512, 0, stream>>>(xfT, t16, out, b0);
  }
}